// Round 5
// baseline (2275.004 us; speedup 1.0000x reference)
//
#include <hip/hip_runtime.h>
#include <hip/hip_cooperative_groups.h>
#include <math.h>

namespace cg = cooperative_groups;

#define MDIM 4096
#define NDIM 4096
#define DDIM 256
#define N_ITER 30

#define TWO_KAPPA 14.426950408889634
#define CLCONST  (-12.0 - TWO_KAPPA)

typedef __attribute__((ext_vector_type(8))) short bf16x8;
typedef __attribute__((ext_vector_type(4))) float f32x4;

// monotone float <-> uint encoding for atomicMax on possibly-negative floats
__device__ __forceinline__ unsigned encf(float f) {
  unsigned u = __float_as_uint(f);
  return (u & 0x80000000u) ? ~u : (u | 0x80000000u);
}
__device__ __forceinline__ float decf(unsigned u) {
  return __uint_as_float((u & 0x80000000u) ? (u ^ 0x80000000u) : ~u);
}
__device__ __forceinline__ unsigned ldvu(const unsigned* p) { return *(const volatile unsigned*)p; }
__device__ __forceinline__ float    ldvf(const float* p)    { return *(const volatile float*)p; }

// ---------- norms: xx[i], yy[j], Sxx ----------
__global__ void norms_kernel(const float* __restrict__ x, const float* __restrict__ y,
                             float* __restrict__ xx, float* __restrict__ yy,
                             float* __restrict__ Sxx) {
  int wid = threadIdx.x >> 6, lane = threadIdx.x & 63;
  int row = blockIdx.x * 4 + wid;
  const float* src = (row < MDIM) ? x : y;
  int r = (row < MDIM) ? row : row - MDIM;
  const float4* p = (const float4*)(src + (size_t)r * DDIM);
  float4 v = p[lane];
  float s = v.x*v.x + v.y*v.y + v.z*v.z + v.w*v.w;
  #pragma unroll
  for (int off = 32; off; off >>= 1) s += __shfl_down(s, off);
  if (lane == 0) {
    if (row < MDIM) { xx[r] = s; atomicAdd(Sxx, s); }
    else            { yy[r] = s; }
  }
}

// ---------- sx[k] = sum_i x[i,k] ----------
__global__ void sx_kernel(const float* __restrict__ x, float* __restrict__ sx) {
  int tx = threadIdx.x;
  int r0 = blockIdx.x * 16;
  float s = 0.f;
  #pragma unroll
  for (int r = 0; r < 16; ++r) s += x[(size_t)(r0 + r) * DDIM + tx];
  atomicAdd(&sx[tx], s);
}

// ---------- colM[j] = Sxx + MDIM*yy[j] - 2*dot(sx, y_j) ----------
__global__ void colM_kernel(const float* __restrict__ y, const float* __restrict__ sx,
                            const float* __restrict__ yy, const float* __restrict__ Sxx,
                            float* __restrict__ colM) {
  int wid = threadIdx.x >> 6, lane = threadIdx.x & 63;
  int j = blockIdx.x * 4 + wid;
  const float4* py = (const float4*)(y + (size_t)j * DDIM);
  const float4* ps = (const float4*)sx;
  float4 a = py[lane], b = ps[lane];
  float s = a.x*b.x + a.y*b.y + a.z*b.z + a.w*b.w;
  #pragma unroll
  for (int off = 32; off; off >>= 1) s += __shfl_down(s, off);
  if (lane == 0) colM[j] = *Sxx + (float)MDIM * yy[j] - 2.f * s;
}

// ---------- split x,y into bf16 hi/lo pairs ----------
__global__ void split_kernel(const float* __restrict__ x, const float* __restrict__ y,
                             ushort* __restrict__ xh, ushort* __restrict__ xl,
                             ushort* __restrict__ yh, ushort* __restrict__ yl) {
  int g = blockIdx.x * 256 + threadIdx.x;   // 0..524287 float4s
  int e; const float4* src; ushort* dh; ushort* dl;
  if (g < 262144) { e = g;          src = (const float4*)x; dh = xh; dl = xl; }
  else            { e = g - 262144; src = (const float4*)y; dh = yh; dl = yl; }
  float4 v = src[e];
  float f[4] = {v.x, v.y, v.z, v.w};
  ushort hs[4], ls[4];
  #pragma unroll
  for (int i = 0; i < 4; ++i) {
    unsigned u = __float_as_uint(f[i]);
    unsigned hr = (u + 0x7FFFu + ((u >> 16) & 1u)) >> 16;
    hs[i] = (ushort)hr;
    float hf = __uint_as_float(hr << 16);
    float lo = f[i] - hf;
    unsigned ul = __float_as_uint(lo);
    unsigned lr = (ul + 0x7FFFu + ((ul >> 16) & 1u)) >> 16;
    ls[i] = (ushort)lr;
  }
  *(ushort4*)(dh + (size_t)e * 4) = make_ushort4(hs[0], hs[1], hs[2], hs[3]);
  *(ushort4*)(dl + (size_t)e * 4) = make_ushort4(ls[0], ls[1], ls[2], ls[3]);
}

// ---------- MFMA GEMM: D16 = round(65536 * (xh.yh + xh.yl + xl.yh)), plus maxdot ----------
#define GPAD 56   // ushorts per LDS row: 32 data + 24 pad (112 B stride, 16B-aligned, 2-way banks)
__global__ __launch_bounds__(256)
void gemm_mfma_kernel(const ushort* __restrict__ xh, const ushort* __restrict__ xl,
                      const ushort* __restrict__ yh, const ushort* __restrict__ yl,
                      short* __restrict__ D16, float* __restrict__ maxdot) {
  __shared__ ushort As[2][128][GPAD];
  __shared__ ushort Bs[2][128][GPAD];
  int tid = threadIdx.x;
  int lane = tid & 63, wid = tid >> 6;
  int bm = blockIdx.x & 31, bn = blockIdx.x >> 5;
  int wrow = (wid >> 1) * 64, wcol = (wid & 1) * 64;
  f32x4 acc[4][4] = {};

  int c0 = tid, c1 = tid + 256;
  int r0 = c0 >> 2, k80 = (c0 & 3) * 8;
  int r1 = c1 >> 2, k81 = (c1 & 3) * 8;
  const size_t arow0 = (size_t)(bm * 128 + r0) * DDIM;
  const size_t arow1 = (size_t)(bm * 128 + r1) * DDIM;
  const size_t brow0 = (size_t)(bn * 128 + r0) * DDIM;
  const size_t brow1 = (size_t)(bn * 128 + r1) * DDIM;

  for (int k0 = 0; k0 < DDIM; k0 += 32) {
    *(uint4*)&As[0][r0][k80] = *(const uint4*)(xh + arow0 + k0 + k80);
    *(uint4*)&As[0][r1][k81] = *(const uint4*)(xh + arow1 + k0 + k81);
    *(uint4*)&As[1][r0][k80] = *(const uint4*)(xl + arow0 + k0 + k80);
    *(uint4*)&As[1][r1][k81] = *(const uint4*)(xl + arow1 + k0 + k81);
    *(uint4*)&Bs[0][r0][k80] = *(const uint4*)(yh + brow0 + k0 + k80);
    *(uint4*)&Bs[0][r1][k81] = *(const uint4*)(yh + brow1 + k0 + k81);
    *(uint4*)&Bs[1][r0][k80] = *(const uint4*)(yl + brow0 + k0 + k80);
    *(uint4*)&Bs[1][r1][k81] = *(const uint4*)(yl + brow1 + k0 + k81);
    __syncthreads();
    int fr = lane & 15, kg = lane >> 4;
    bf16x8 ah[4], al[4], bh[4], bl[4];
    #pragma unroll
    for (int i = 0; i < 4; ++i) {
      ah[i] = *(const bf16x8*)&As[0][wrow + i * 16 + fr][kg * 8];
      al[i] = *(const bf16x8*)&As[1][wrow + i * 16 + fr][kg * 8];
      bh[i] = *(const bf16x8*)&Bs[0][wcol + i * 16 + fr][kg * 8];
      bl[i] = *(const bf16x8*)&Bs[1][wcol + i * 16 + fr][kg * 8];
    }
    #pragma unroll
    for (int i = 0; i < 4; ++i)
      #pragma unroll
      for (int j = 0; j < 4; ++j) {
        acc[i][j] = __builtin_amdgcn_mfma_f32_16x16x32_bf16(ah[i], bh[j], acc[i][j], 0, 0, 0);
        acc[i][j] = __builtin_amdgcn_mfma_f32_16x16x32_bf16(ah[i], bl[j], acc[i][j], 0, 0, 0);
        acc[i][j] = __builtin_amdgcn_mfma_f32_16x16x32_bf16(al[i], bh[j], acc[i][j], 0, 0, 0);
      }
    __syncthreads();
  }
  // epilogue: C/D layout col=lane&15, row=(lane>>4)*4+reg  [m89-verified]
  float tmax = -1.f;
  #pragma unroll
  for (int i = 0; i < 4; ++i) {
    #pragma unroll
    for (int j = 0; j < 4; ++j) {
      int col = bn * 128 + wcol + j * 16 + (lane & 15);
      #pragma unroll
      for (int r = 0; r < 4; ++r) {
        float d = acc[i][j][r];
        tmax = fmaxf(tmax, d);
        int q = __float2int_rn(fminf(fmaxf(d * 65536.f, -32767.f), 32767.f));
        int row = bm * 128 + wrow + i * 16 + (lane >> 4) * 4 + r;
        D16[(size_t)row * NDIM + col] = (short)q;
      }
    }
  }
  __shared__ float sm[4];
  #pragma unroll
  for (int off = 32; off; off >>= 1) tmax = fmaxf(tmax, __shfl_down(tmax, off));
  if (lane == 0) sm[wid] = tmax;
  __syncthreads();
  if (tid == 0) {
    float m = fmaxf(fmaxf(sm[0], sm[1]), fmaxf(sm[2], sm[3]));
    atomicMax((int*)maxdot, __float_as_int(fmaxf(m, 0.f)));
  }
}

// ---------- fused 30-iteration cooperative solver ----------
__global__ __launch_bounds__(1024)
void solve_kernel(const short* __restrict__ D16, float* __restrict__ partial,
                  float* __restrict__ phi, float* __restrict__ psi,
                  const float* __restrict__ maxdot,
                  unsigned* psimaxU, unsigned* phimaxU,
                  const float* __restrict__ colM,
                  float* lossacc, float* __restrict__ out) {
  cg::grid_group gg = cg::this_grid();
  __shared__ float rp[16][17];
  __shared__ float bred[16][17];
  int tid = threadIdx.x, lane = tid & 63, wid = tid >> 6;
  int blk = blockIdx.x;
  int row0 = blk * 16;
  int j0 = tid * 4;
  float md = maxdot[0];

  for (int t = 1; t <= N_ITER; ++t) {
    float sD  = (float)((double)t * (TWO_KAPPA / 65536.0));
    float tCL = (float)((double)t * CLCONST);
    float s2k = (float)((double)t * TWO_KAPPA);
    float tLmax = fmaf(s2k, md, tCL);
    float psimax, phimax, p0, p1, p2, p3;
    if (t == 1) { psimax = phimax = -6.f; p0 = p1 = p2 = p3 = -6.f; }
    else {
      psimax = decf(ldvu(&psimaxU[t]));
      phimax = decf(ldvu(&phimaxU[t]));
      float4 pv = *(const float4*)(psi + j0);
      p0 = pv.x; p1 = pv.y; p2 = pv.z; p3 = pv.w;
    }
    float Sr = tLmax + psimax - 100.f;
    float Sc = tLmax + phimax - 100.f;
    float W  = tCL - Sr;
    float Wc = tCL - Sc;
    float P0 = p0 + W, P1 = p1 + W, P2 = p2 + W, P3 = p3 + W;

    // ---- phase A: row sums -> phi_{t+1}; column partials -> partial[blk] ----
    float c0 = 0.f, c1 = 0.f, c2 = 0.f, c3 = 0.f;
    #pragma unroll 4
    for (int r = 0; r < 16; ++r) {
      int row = row0 + r;
      float phi_row = (t == 1) ? -6.f : phi[row];
      float Crow = Wc + phi_row;
      int2 dv = *(const int2*)(D16 + (size_t)row * NDIM + j0);
      float d0 = (float)((short)(dv.x & 0xFFFF));
      float d1 = (float)(dv.x >> 16);
      float d2 = (float)((short)(dv.y & 0xFFFF));
      float d3 = (float)(dv.y >> 16);
      c0 += exp2f(fmaf(d0, sD, Crow));
      c1 += exp2f(fmaf(d1, sD, Crow));
      c2 += exp2f(fmaf(d2, sD, Crow));
      c3 += exp2f(fmaf(d3, sD, Crow));
      float racc = exp2f(fmaf(d0, sD, P0)) + exp2f(fmaf(d1, sD, P1))
                 + exp2f(fmaf(d2, sD, P2)) + exp2f(fmaf(d3, sD, P3));
      #pragma unroll
      for (int off = 32; off; off >>= 1) racc += __shfl_down(racc, off);
      if (lane == 0) rp[r][wid] = racc;
    }
    __syncthreads();
    if (tid < 16) {
      float s = 0.f;
      #pragma unroll
      for (int w = 0; w < 16; ++w) s += rp[tid][w];
      int row = row0 + tid;
      float phi_row = (t == 1) ? -6.f : phi[row];
      float pn = 0.5f * (phi_row - Sr - log2f(fmaxf(s, 1e-30f)));
      phi[row] = pn;
      #pragma unroll
      for (int o = 8; o; o >>= 1) pn = fmaxf(pn, __shfl_down(pn, o));
      if (tid == 0) atomicMax(&phimaxU[t + 1], encf(pn));
    }
    *(float4*)(partial + (size_t)blk * NDIM + j0) = make_float4(c0, c1, c2, c3);
    gg.sync();

    // ---- phase B: block blk reduces columns [blk*16, blk*16+16) ----
    {
      int cloc = tid & 15, bgrp = tid >> 4;
      int j = blk * 16 + cloc;
      float s = partial[(size_t)bgrp * NDIM + j]
              + partial[(size_t)(bgrp + 64) * NDIM + j]
              + partial[(size_t)(bgrp + 128) * NDIM + j]
              + partial[(size_t)(bgrp + 192) * NDIM + j];
      s += __shfl_xor(s, 16);
      s += __shfl_xor(s, 32);
      if (lane < 16) bred[wid][lane] = s;
      __syncthreads();
      if (tid < 16) {
        float tot = bred[0][tid];
        #pragma unroll
        for (int w = 1; w < 16; ++w) tot += bred[w][tid];
        int jj = blk * 16 + tid;
        if (t < N_ITER) {
          float psiv = (t == 1) ? -6.f : psi[jj];
          float pn = 0.5f * (psiv - Sc - log2f(fmaxf(tot, 1e-30f)));
          psi[jj] = pn;
          #pragma unroll
          for (int o = 8; o; o >>= 1) pn = fmaxf(pn, __shfl_down(pn, o));
          if (tid == 0) atomicMax(&psimaxU[t + 1], encf(pn));
        } else {
          // t == 30: colsum_j = 2^{psi30_j + Sc30} * tot; loss contrib = colsum_j * colM_j
          float contrib = exp2f(log2f(fmaxf(tot, 1e-30f)) + psi[jj] + Sc + log2f(colM[jj]));
          #pragma unroll
          for (int o = 8; o; o >>= 1) contrib += __shfl_down(contrib, o);
          if (tid == 0) atomicAdd(lossacc, contrib);
        }
      }
      __syncthreads();
    }
    gg.sync();
  }
  if (blk == 0 && tid == 0)
    out[0] = ldvf(lossacc) * (1.f / ((float)MDIM * (float)MDIM));
}

extern "C" void kernel_launch(void* const* d_in, const int* in_sizes, int n_in,
                              void* d_out, int out_size, void* d_ws, size_t ws_size,
                              hipStream_t stream) {
  const float* x = (const float*)d_in[0];
  const float* y = (const float*)d_in[1];
  float* out = (float*)d_out;

  char* ws = (char*)d_ws;
  size_t off = 0;
  auto alloc = [&](size_t bytes) -> void* {
    void* p = ws + off;
    off += (bytes + 255) & ~(size_t)255;
    return p;
  };
  short*    D16     = (short*)alloc((size_t)MDIM * NDIM * 2);      // 32 MB
  float*    partial = (float*)alloc((size_t)256 * NDIM * 4);       // 4 MB
  ushort*   xh      = (ushort*)alloc((size_t)MDIM * DDIM * 2);
  ushort*   xl      = (ushort*)alloc((size_t)MDIM * DDIM * 2);
  ushort*   yh      = (ushort*)alloc((size_t)NDIM * DDIM * 2);
  ushort*   yl      = (ushort*)alloc((size_t)NDIM * DDIM * 2);
  float*    xx      = (float*)alloc(MDIM * 4);
  float*    yy      = (float*)alloc(NDIM * 4);
  float*    sx      = (float*)alloc(DDIM * 4);
  float*    colM    = (float*)alloc(NDIM * 4);
  float*    Sxx     = (float*)alloc(4);
  float*    maxd    = (float*)alloc(4);
  unsigned* psimaxU = (unsigned*)alloc(64 * 4);
  unsigned* phimaxU = (unsigned*)alloc(64 * 4);
  float*    phi     = (float*)alloc(MDIM * 4);
  float*    psi     = (float*)alloc(NDIM * 4);
  float*    lossacc = (float*)alloc(4);

  hipMemsetAsync(Sxx, 0, 4, stream);
  hipMemsetAsync(maxd, 0, 4, stream);
  hipMemsetAsync(sx, 0, DDIM * 4, stream);
  hipMemsetAsync(psimaxU, 0, 64 * 4, stream);
  hipMemsetAsync(phimaxU, 0, 64 * 4, stream);
  hipMemsetAsync(lossacc, 0, 4, stream);

  norms_kernel<<<2048, 256, 0, stream>>>(x, y, xx, yy, Sxx);
  sx_kernel<<<256, 256, 0, stream>>>(x, sx);
  colM_kernel<<<1024, 256, 0, stream>>>(y, sx, yy, Sxx, colM);
  split_kernel<<<2048, 256, 0, stream>>>(x, y, xh, xl, yh, yl);
  gemm_mfma_kernel<<<1024, 256, 0, stream>>>(xh, xl, yh, yl, D16, maxd);

  void* kargs[] = {(void*)&D16, (void*)&partial, (void*)&phi, (void*)&psi,
                   (void*)&maxd, (void*)&psimaxU, (void*)&phimaxU,
                   (void*)&colM, (void*)&lossacc, (void*)&out};
  hipLaunchCooperativeKernel((void*)solve_kernel, dim3(256), dim3(1024),
                             kargs, 0, stream);
}

// Round 6
// 1319.634 us; speedup vs baseline: 1.7240x; 1.7240x over previous
//
#include <hip/hip_runtime.h>
#include <math.h>

#define MDIM 4096
#define NDIM 4096
#define DDIM 256
#define N_ITER 30

#define TWO_KAPPA 14.426950408889634
#define CLCONST  (-12.0 - TWO_KAPPA)

typedef __attribute__((ext_vector_type(8))) short bf16x8;
typedef __attribute__((ext_vector_type(4))) float f32x4;

// monotone float <-> uint encoding for atomicMax on possibly-negative floats
__device__ __forceinline__ unsigned encf(float f) {
  unsigned u = __float_as_uint(f);
  return (u & 0x80000000u) ? ~u : (u | 0x80000000u);
}
__device__ __forceinline__ float decf(unsigned u) {
  return __uint_as_float((u & 0x80000000u) ? (u ^ 0x80000000u) : ~u);
}
__device__ __forceinline__ unsigned ldvu(const unsigned* p) { return *(const volatile unsigned*)p; }
__device__ __forceinline__ float    ldvf(const float* p)    { return *(const volatile float*)p; }

// ---------- norms: xx[i], yy[j], Sxx ----------
__global__ void norms_kernel(const float* __restrict__ x, const float* __restrict__ y,
                             float* __restrict__ xx, float* __restrict__ yy,
                             float* __restrict__ Sxx) {
  int wid = threadIdx.x >> 6, lane = threadIdx.x & 63;
  int row = blockIdx.x * 4 + wid;
  const float* src = (row < MDIM) ? x : y;
  int r = (row < MDIM) ? row : row - MDIM;
  const float4* p = (const float4*)(src + (size_t)r * DDIM);
  float4 v = p[lane];
  float s = v.x*v.x + v.y*v.y + v.z*v.z + v.w*v.w;
  #pragma unroll
  for (int off = 32; off; off >>= 1) s += __shfl_down(s, off);
  if (lane == 0) {
    if (row < MDIM) { xx[r] = s; atomicAdd(Sxx, s); }
    else            { yy[r] = s; }
  }
}

// ---------- sx[k] = sum_i x[i,k] ----------
__global__ void sx_kernel(const float* __restrict__ x, float* __restrict__ sx) {
  int tx = threadIdx.x;
  int r0 = blockIdx.x * 16;
  float s = 0.f;
  #pragma unroll
  for (int r = 0; r < 16; ++r) s += x[(size_t)(r0 + r) * DDIM + tx];
  atomicAdd(&sx[tx], s);
}

// ---------- colM[j] = Sxx + MDIM*yy[j] - 2*dot(sx, y_j) ----------
__global__ void colM_kernel(const float* __restrict__ y, const float* __restrict__ sx,
                            const float* __restrict__ yy, const float* __restrict__ Sxx,
                            float* __restrict__ colM) {
  int wid = threadIdx.x >> 6, lane = threadIdx.x & 63;
  int j = blockIdx.x * 4 + wid;
  const float4* py = (const float4*)(y + (size_t)j * DDIM);
  const float4* ps = (const float4*)sx;
  float4 a = py[lane], b = ps[lane];
  float s = a.x*b.x + a.y*b.y + a.z*b.z + a.w*b.w;
  #pragma unroll
  for (int off = 32; off; off >>= 1) s += __shfl_down(s, off);
  if (lane == 0) colM[j] = *Sxx + (float)MDIM * yy[j] - 2.f * s;
}

// ---------- split x,y into bf16 hi/lo pairs ----------
__global__ void split_kernel(const float* __restrict__ x, const float* __restrict__ y,
                             ushort* __restrict__ xh, ushort* __restrict__ xl,
                             ushort* __restrict__ yh, ushort* __restrict__ yl) {
  int g = blockIdx.x * 256 + threadIdx.x;
  int e; const float4* src; ushort* dh; ushort* dl;
  if (g < 262144) { e = g;          src = (const float4*)x; dh = xh; dl = xl; }
  else            { e = g - 262144; src = (const float4*)y; dh = yh; dl = yl; }
  float4 v = src[e];
  float f[4] = {v.x, v.y, v.z, v.w};
  ushort hs[4], ls[4];
  #pragma unroll
  for (int i = 0; i < 4; ++i) {
    unsigned u = __float_as_uint(f[i]);
    unsigned hr = (u + 0x7FFFu + ((u >> 16) & 1u)) >> 16;
    hs[i] = (ushort)hr;
    float hf = __uint_as_float(hr << 16);
    float lo = f[i] - hf;
    unsigned ul = __float_as_uint(lo);
    unsigned lr = (ul + 0x7FFFu + ((ul >> 16) & 1u)) >> 16;
    ls[i] = (ushort)lr;
  }
  *(ushort4*)(dh + (size_t)e * 4) = make_ushort4(hs[0], hs[1], hs[2], hs[3]);
  *(ushort4*)(dl + (size_t)e * 4) = make_ushort4(ls[0], ls[1], ls[2], ls[3]);
}

// ---------- MFMA GEMM: D16 = round(65536 * (xh.yh + xh.yl + xl.yh)), plus maxdot ----------
#define GPAD 56
__global__ __launch_bounds__(256)
void gemm_mfma_kernel(const ushort* __restrict__ xh, const ushort* __restrict__ xl,
                      const ushort* __restrict__ yh, const ushort* __restrict__ yl,
                      short* __restrict__ D16, float* __restrict__ maxdot) {
  __shared__ ushort As[2][128][GPAD];
  __shared__ ushort Bs[2][128][GPAD];
  int tid = threadIdx.x;
  int lane = tid & 63, wid = tid >> 6;
  int bm = blockIdx.x & 31, bn = blockIdx.x >> 5;
  int wrow = (wid >> 1) * 64, wcol = (wid & 1) * 64;
  f32x4 acc[4][4] = {};

  int c0 = tid, c1 = tid + 256;
  int r0 = c0 >> 2, k80 = (c0 & 3) * 8;
  int r1 = c1 >> 2, k81 = (c1 & 3) * 8;
  const size_t arow0 = (size_t)(bm * 128 + r0) * DDIM;
  const size_t arow1 = (size_t)(bm * 128 + r1) * DDIM;
  const size_t brow0 = (size_t)(bn * 128 + r0) * DDIM;
  const size_t brow1 = (size_t)(bn * 128 + r1) * DDIM;

  for (int k0 = 0; k0 < DDIM; k0 += 32) {
    *(uint4*)&As[0][r0][k80] = *(const uint4*)(xh + arow0 + k0 + k80);
    *(uint4*)&As[0][r1][k81] = *(const uint4*)(xh + arow1 + k0 + k81);
    *(uint4*)&As[1][r0][k80] = *(const uint4*)(xl + arow0 + k0 + k80);
    *(uint4*)&As[1][r1][k81] = *(const uint4*)(xl + arow1 + k0 + k81);
    *(uint4*)&Bs[0][r0][k80] = *(const uint4*)(yh + brow0 + k0 + k80);
    *(uint4*)&Bs[0][r1][k81] = *(const uint4*)(yh + brow1 + k0 + k81);
    *(uint4*)&Bs[1][r0][k80] = *(const uint4*)(yl + brow0 + k0 + k80);
    *(uint4*)&Bs[1][r1][k81] = *(const uint4*)(yl + brow1 + k0 + k81);
    __syncthreads();
    int fr = lane & 15, kg = lane >> 4;
    bf16x8 ah[4], al[4], bh[4], bl[4];
    #pragma unroll
    for (int i = 0; i < 4; ++i) {
      ah[i] = *(const bf16x8*)&As[0][wrow + i * 16 + fr][kg * 8];
      al[i] = *(const bf16x8*)&As[1][wrow + i * 16 + fr][kg * 8];
      bh[i] = *(const bf16x8*)&Bs[0][wcol + i * 16 + fr][kg * 8];
      bl[i] = *(const bf16x8*)&Bs[1][wcol + i * 16 + fr][kg * 8];
    }
    #pragma unroll
    for (int i = 0; i < 4; ++i)
      #pragma unroll
      for (int j = 0; j < 4; ++j) {
        acc[i][j] = __builtin_amdgcn_mfma_f32_16x16x32_bf16(ah[i], bh[j], acc[i][j], 0, 0, 0);
        acc[i][j] = __builtin_amdgcn_mfma_f32_16x16x32_bf16(ah[i], bl[j], acc[i][j], 0, 0, 0);
        acc[i][j] = __builtin_amdgcn_mfma_f32_16x16x32_bf16(al[i], bh[j], acc[i][j], 0, 0, 0);
      }
    __syncthreads();
  }
  float tmax = -1.f;
  #pragma unroll
  for (int i = 0; i < 4; ++i) {
    #pragma unroll
    for (int j = 0; j < 4; ++j) {
      int col = bn * 128 + wcol + j * 16 + (lane & 15);
      #pragma unroll
      for (int r = 0; r < 4; ++r) {
        float d = acc[i][j][r];
        tmax = fmaxf(tmax, d);
        int q = __float2int_rn(fminf(fmaxf(d * 65536.f, -32767.f), 32767.f));
        int row = bm * 128 + wrow + i * 16 + (lane >> 4) * 4 + r;
        D16[(size_t)row * NDIM + col] = (short)q;
      }
    }
  }
  __shared__ float sm[4];
  #pragma unroll
  for (int off = 32; off; off >>= 1) tmax = fmaxf(tmax, __shfl_down(tmax, off));
  if (lane == 0) sm[wid] = tmax;
  __syncthreads();
  if (tid == 0) {
    float m = fmaxf(fmaxf(sm[0], sm[1]), fmaxf(sm[2], sm[3]));
    atomicMax((int*)maxdot, __float_as_int(fmaxf(m, 0.f)));
  }
}

// ---------- lightweight sharded grid barrier (agent scope) ----------
// cnt layout: [barrier b][shard s] strided 16 uints (64 B). root: [b] strided 16.
__device__ __forceinline__ void gridbar(unsigned* cnt, unsigned* root, int b, int blk) {
  __syncthreads();
  if (threadIdx.x == 0) {
    unsigned* sc = cnt + ((b << 4) + (blk & 15)) * 16;
    unsigned old = __hip_atomic_fetch_add(sc, 1u, __ATOMIC_ACQ_REL, __HIP_MEMORY_SCOPE_AGENT);
    if (old == 15u) {  // last of this shard's 16 blocks
      __hip_atomic_fetch_add(root + b * 16, 1u, __ATOMIC_ACQ_REL, __HIP_MEMORY_SCOPE_AGENT);
    }
    while (__hip_atomic_load(root + b * 16, __ATOMIC_RELAXED, __HIP_MEMORY_SCOPE_AGENT) < 16u)
      __builtin_amdgcn_s_sleep(1);
    (void)__hip_atomic_load(root + b * 16, __ATOMIC_ACQUIRE, __HIP_MEMORY_SCOPE_AGENT);
  }
  __syncthreads();
}

// ---------- fused 30-iteration persistent solver (D16 register-resident) ----------
__global__ __launch_bounds__(1024, 4)
void solve_kernel(const short* __restrict__ D16, float* __restrict__ partial,
                  float* __restrict__ psi,
                  const float* __restrict__ maxdot,
                  unsigned* psimaxS, unsigned* phimaxS,
                  const float* __restrict__ colM,
                  float* lossacc, float* __restrict__ out,
                  unsigned* cnt, unsigned* root) {
  __shared__ float rp[16][17];
  __shared__ float bred[16][17];
  __shared__ float phi_lds[16];
  int tid = threadIdx.x, lane = tid & 63, wid = tid >> 6;
  int blk = blockIdx.x;
  int row0 = blk * 16;
  int j0 = tid * 4;
  float md = maxdot[0];

  // one-time: pull this thread's 16x4 stripe of D16 into registers (32 VGPR)
  int2 d[16];
  #pragma unroll
  for (int r = 0; r < 16; ++r)
    d[r] = *(const int2*)(D16 + (size_t)(row0 + r) * NDIM + j0);

  if (tid < 16) phi_lds[tid] = -6.f;
  __syncthreads();

  for (int t = 1; t <= N_ITER; ++t) {
    float sD  = (float)((double)t * (TWO_KAPPA / 65536.0));
    float tCL = (float)((double)t * CLCONST);
    float s2k = (float)((double)t * TWO_KAPPA);
    float tLmax = fmaf(s2k, md, tCL);
    float psimax, phimax, p0, p1, p2, p3;
    if (t == 1) { psimax = phimax = -6.f; p0 = p1 = p2 = p3 = -6.f; }
    else {
      unsigned up = 0, uf = 0;
      #pragma unroll
      for (int s = 0; s < 16; ++s) {
        unsigned a = ldvu(&psimaxS[(t << 4) + s]); up = (a > up) ? a : up;
        unsigned b = ldvu(&phimaxS[(t << 4) + s]); uf = (b > uf) ? b : uf;
      }
      psimax = decf(up);
      phimax = decf(uf);
      float4 pv = *(const float4*)(psi + j0);
      p0 = pv.x; p1 = pv.y; p2 = pv.z; p3 = pv.w;
    }
    float Sr = tLmax + psimax - 100.f;
    float Sc = tLmax + phimax - 100.f;
    float W  = tCL - Sr;
    float Wc = tCL - Sc;
    float P0 = p0 + W, P1 = p1 + W, P2 = p2 + W, P3 = p3 + W;

    // ---- phase A: row sums -> phi (LDS) + sharded phimax; col partials -> partial[blk] ----
    float c0 = 0.f, c1 = 0.f, c2 = 0.f, c3 = 0.f;
    #pragma unroll
    for (int r = 0; r < 16; ++r) {
      float Crow = Wc + phi_lds[r];
      int2 dv = d[r];
      float d0 = (float)((short)(dv.x & 0xFFFF));
      float d1 = (float)(dv.x >> 16);
      float d2 = (float)((short)(dv.y & 0xFFFF));
      float d3 = (float)(dv.y >> 16);
      c0 += exp2f(fmaf(d0, sD, Crow));
      c1 += exp2f(fmaf(d1, sD, Crow));
      c2 += exp2f(fmaf(d2, sD, Crow));
      c3 += exp2f(fmaf(d3, sD, Crow));
      float racc = exp2f(fmaf(d0, sD, P0)) + exp2f(fmaf(d1, sD, P1))
                 + exp2f(fmaf(d2, sD, P2)) + exp2f(fmaf(d3, sD, P3));
      #pragma unroll
      for (int off = 32; off; off >>= 1) racc += __shfl_down(racc, off);
      if (lane == 0) rp[r][wid] = racc;
    }
    __syncthreads();
    if (tid < 16) {
      float s = 0.f;
      #pragma unroll
      for (int w = 0; w < 16; ++w) s += rp[tid][w];
      float pn = 0.5f * (phi_lds[tid] - Sr - log2f(fmaxf(s, 1e-30f)));
      phi_lds[tid] = pn;
      #pragma unroll
      for (int o = 8; o; o >>= 1) pn = fmaxf(pn, __shfl_down(pn, o));
      if (tid == 0) atomicMax(&phimaxS[((t + 1) << 4) + (blk & 15)], encf(pn));
    }
    *(float4*)(partial + (size_t)blk * NDIM + j0) = make_float4(c0, c1, c2, c3);
    gridbar(cnt, root, 2 * t - 2, blk);

    // ---- phase B: block reduces columns [blk*16, blk*16+16) ----
    {
      int cloc = tid & 15, bgrp = tid >> 4;
      int j = blk * 16 + cloc;
      float s = partial[(size_t)bgrp * NDIM + j]
              + partial[(size_t)(bgrp + 64) * NDIM + j]
              + partial[(size_t)(bgrp + 128) * NDIM + j]
              + partial[(size_t)(bgrp + 192) * NDIM + j];
      s += __shfl_xor(s, 16);
      s += __shfl_xor(s, 32);
      if (lane < 16) bred[wid][lane] = s;
      __syncthreads();
      if (tid < 16) {
        float tot = bred[0][tid];
        #pragma unroll
        for (int w = 1; w < 16; ++w) tot += bred[w][tid];
        int jj = blk * 16 + tid;
        if (t < N_ITER) {
          float psiv = (t == 1) ? -6.f : psi[jj];
          float pn = 0.5f * (psiv - Sc - log2f(fmaxf(tot, 1e-30f)));
          psi[jj] = pn;
          #pragma unroll
          for (int o = 8; o; o >>= 1) pn = fmaxf(pn, __shfl_down(pn, o));
          if (tid == 0) atomicMax(&psimaxS[((t + 1) << 4) + (blk & 15)], encf(pn));
        } else {
          float contrib = exp2f(log2f(fmaxf(tot, 1e-30f)) + psi[jj] + Sc + log2f(colM[jj]));
          #pragma unroll
          for (int o = 8; o; o >>= 1) contrib += __shfl_down(contrib, o);
          if (tid == 0) atomicAdd(&lossacc[blk & 15], contrib);
        }
      }
      __syncthreads();
    }
    gridbar(cnt, root, 2 * t - 1, blk);
  }
  if (blk == 0 && tid == 0) {
    float tot = 0.f;
    #pragma unroll
    for (int s = 0; s < 16; ++s) tot += ldvf(&lossacc[s]);
    out[0] = tot * (1.f / ((float)MDIM * (float)MDIM));
  }
}

extern "C" void kernel_launch(void* const* d_in, const int* in_sizes, int n_in,
                              void* d_out, int out_size, void* d_ws, size_t ws_size,
                              hipStream_t stream) {
  const float* x = (const float*)d_in[0];
  const float* y = (const float*)d_in[1];
  float* out = (float*)d_out;

  char* ws = (char*)d_ws;
  size_t off = 0;
  auto alloc = [&](size_t bytes) -> void* {
    void* p = ws + off;
    off += (bytes + 255) & ~(size_t)255;
    return p;
  };
  short*    D16     = (short*)alloc((size_t)MDIM * NDIM * 2);      // 32 MB
  float*    partial = (float*)alloc((size_t)256 * NDIM * 4);       // 4 MB
  ushort*   xh      = (ushort*)alloc((size_t)MDIM * DDIM * 2);
  ushort*   xl      = (ushort*)alloc((size_t)MDIM * DDIM * 2);
  ushort*   yh      = (ushort*)alloc((size_t)NDIM * DDIM * 2);
  ushort*   yl      = (ushort*)alloc((size_t)NDIM * DDIM * 2);
  float*    xx      = (float*)alloc(MDIM * 4);
  float*    yy      = (float*)alloc(NDIM * 4);
  float*    sx      = (float*)alloc(DDIM * 4);
  float*    colM    = (float*)alloc(NDIM * 4);
  float*    Sxx     = (float*)alloc(4);
  float*    maxd    = (float*)alloc(4);
  unsigned* psimaxS = (unsigned*)alloc(64 * 16 * 4);
  unsigned* phimaxS = (unsigned*)alloc(64 * 16 * 4);
  float*    psi     = (float*)alloc(NDIM * 4);
  float*    lossacc = (float*)alloc(16 * 4);
  unsigned* cnt     = (unsigned*)alloc(64 * 16 * 16 * 4);          // 64 KB
  unsigned* root    = (unsigned*)alloc(64 * 16 * 4);               // 4 KB

  hipMemsetAsync(Sxx, 0, 4, stream);
  hipMemsetAsync(maxd, 0, 4, stream);
  hipMemsetAsync(sx, 0, DDIM * 4, stream);
  hipMemsetAsync(psimaxS, 0, 64 * 16 * 4, stream);
  hipMemsetAsync(phimaxS, 0, 64 * 16 * 4, stream);
  hipMemsetAsync(lossacc, 0, 16 * 4, stream);
  hipMemsetAsync(cnt, 0, 64 * 16 * 16 * 4, stream);
  hipMemsetAsync(root, 0, 64 * 16 * 4, stream);

  norms_kernel<<<2048, 256, 0, stream>>>(x, y, xx, yy, Sxx);
  sx_kernel<<<256, 256, 0, stream>>>(x, sx);
  colM_kernel<<<1024, 256, 0, stream>>>(y, sx, yy, Sxx, colM);
  split_kernel<<<2048, 256, 0, stream>>>(x, y, xh, xl, yh, yl);
  gemm_mfma_kernel<<<1024, 256, 0, stream>>>(xh, xl, yh, yl, D16, maxd);

  void* kargs[] = {(void*)&D16, (void*)&partial, (void*)&psi,
                   (void*)&maxd, (void*)&psimaxS, (void*)&phimaxS,
                   (void*)&colM, (void*)&lossacc, (void*)&out,
                   (void*)&cnt, (void*)&root};
  hipLaunchCooperativeKernel((void*)solve_kernel, dim3(256), dim3(1024),
                             kargs, 0, stream);
}

// Round 7
// 1005.720 us; speedup vs baseline: 2.2621x; 1.3121x over previous
//
#include <hip/hip_runtime.h>
#include <math.h>

#define MDIM 4096
#define NDIM 4096
#define DDIM 256
#define N_ITER 30

#define TWO_KAPPA 14.426950408889634
#define CLCONST  (-12.0 - TWO_KAPPA)

typedef __attribute__((ext_vector_type(8))) short bf16x8;
typedef __attribute__((ext_vector_type(4))) float f32x4;

__device__ __forceinline__ unsigned encf(float f) {
  unsigned u = __float_as_uint(f);
  return (u & 0x80000000u) ? ~u : (u | 0x80000000u);
}
__device__ __forceinline__ float decf(unsigned u) {
  return __uint_as_float((u & 0x80000000u) ? (u ^ 0x80000000u) : ~u);
}
__device__ __forceinline__ unsigned ldvu(const unsigned* p) { return *(const volatile unsigned*)p; }
__device__ __forceinline__ float    ldvf(const float* p)    { return *(const volatile float*)p; }

// ---------- norms: xx[i], yy[j], Sxx ----------
__global__ void norms_kernel(const float* __restrict__ x, const float* __restrict__ y,
                             float* __restrict__ xx, float* __restrict__ yy,
                             float* __restrict__ Sxx) {
  int wid = threadIdx.x >> 6, lane = threadIdx.x & 63;
  int row = blockIdx.x * 4 + wid;
  const float* src = (row < MDIM) ? x : y;
  int r = (row < MDIM) ? row : row - MDIM;
  const float4* p = (const float4*)(src + (size_t)r * DDIM);
  float4 v = p[lane];
  float s = v.x*v.x + v.y*v.y + v.z*v.z + v.w*v.w;
  #pragma unroll
  for (int off = 32; off; off >>= 1) s += __shfl_down(s, off);
  if (lane == 0) {
    if (row < MDIM) { xx[r] = s; atomicAdd(Sxx, s); }
    else            { yy[r] = s; }
  }
}

// ---------- sx[k] = sum_i x[i,k] ----------
__global__ void sx_kernel(const float* __restrict__ x, float* __restrict__ sx) {
  int tx = threadIdx.x;
  int r0 = blockIdx.x * 16;
  float s = 0.f;
  #pragma unroll
  for (int r = 0; r < 16; ++r) s += x[(size_t)(r0 + r) * DDIM + tx];
  atomicAdd(&sx[tx], s);
}

// ---------- colM[j] = Sxx + MDIM*yy[j] - 2*dot(sx, y_j) ----------
__global__ void colM_kernel(const float* __restrict__ y, const float* __restrict__ sx,
                            const float* __restrict__ yy, const float* __restrict__ Sxx,
                            float* __restrict__ colM) {
  int wid = threadIdx.x >> 6, lane = threadIdx.x & 63;
  int j = blockIdx.x * 4 + wid;
  const float4* py = (const float4*)(y + (size_t)j * DDIM);
  const float4* ps = (const float4*)sx;
  float4 a = py[lane], b = ps[lane];
  float s = a.x*b.x + a.y*b.y + a.z*b.z + a.w*b.w;
  #pragma unroll
  for (int off = 32; off; off >>= 1) s += __shfl_down(s, off);
  if (lane == 0) colM[j] = *Sxx + (float)MDIM * yy[j] - 2.f * s;
}

// ---------- split x,y into bf16 hi/lo pairs ----------
__global__ void split_kernel(const float* __restrict__ x, const float* __restrict__ y,
                             ushort* __restrict__ xh, ushort* __restrict__ xl,
                             ushort* __restrict__ yh, ushort* __restrict__ yl) {
  int g = blockIdx.x * 256 + threadIdx.x;
  int e; const float4* src; ushort* dh; ushort* dl;
  if (g < 262144) { e = g;          src = (const float4*)x; dh = xh; dl = xl; }
  else            { e = g - 262144; src = (const float4*)y; dh = yh; dl = yl; }
  float4 v = src[e];
  float f[4] = {v.x, v.y, v.z, v.w};
  ushort hs[4], ls[4];
  #pragma unroll
  for (int i = 0; i < 4; ++i) {
    unsigned u = __float_as_uint(f[i]);
    unsigned hr = (u + 0x7FFFu + ((u >> 16) & 1u)) >> 16;
    hs[i] = (ushort)hr;
    float hf = __uint_as_float(hr << 16);
    float lo = f[i] - hf;
    unsigned ul = __float_as_uint(lo);
    unsigned lr = (ul + 0x7FFFu + ((ul >> 16) & 1u)) >> 16;
    ls[i] = (ushort)lr;
  }
  *(ushort4*)(dh + (size_t)e * 4) = make_ushort4(hs[0], hs[1], hs[2], hs[3]);
  *(ushort4*)(dl + (size_t)e * 4) = make_ushort4(ls[0], ls[1], ls[2], ls[3]);
}

// ---------- MFMA GEMM: D16 = round(65536 * (xh.yh + xh.yl + xl.yh)), plus maxdot ----------
#define GPAD 56
__global__ __launch_bounds__(256)
void gemm_mfma_kernel(const ushort* __restrict__ xh, const ushort* __restrict__ xl,
                      const ushort* __restrict__ yh, const ushort* __restrict__ yl,
                      short* __restrict__ D16, float* __restrict__ maxdot) {
  __shared__ ushort As[2][128][GPAD];
  __shared__ ushort Bs[2][128][GPAD];
  int tid = threadIdx.x;
  int lane = tid & 63, wid = tid >> 6;
  int bm = blockIdx.x & 31, bn = blockIdx.x >> 5;
  int wrow = (wid >> 1) * 64, wcol = (wid & 1) * 64;
  f32x4 acc[4][4] = {};

  int c0 = tid, c1 = tid + 256;
  int r0 = c0 >> 2, k80 = (c0 & 3) * 8;
  int r1 = c1 >> 2, k81 = (c1 & 3) * 8;
  const size_t arow0 = (size_t)(bm * 128 + r0) * DDIM;
  const size_t arow1 = (size_t)(bm * 128 + r1) * DDIM;
  const size_t brow0 = (size_t)(bn * 128 + r0) * DDIM;
  const size_t brow1 = (size_t)(bn * 128 + r1) * DDIM;

  for (int k0 = 0; k0 < DDIM; k0 += 32) {
    *(uint4*)&As[0][r0][k80] = *(const uint4*)(xh + arow0 + k0 + k80);
    *(uint4*)&As[0][r1][k81] = *(const uint4*)(xh + arow1 + k0 + k81);
    *(uint4*)&As[1][r0][k80] = *(const uint4*)(xl + arow0 + k0 + k80);
    *(uint4*)&As[1][r1][k81] = *(const uint4*)(xl + arow1 + k0 + k81);
    *(uint4*)&Bs[0][r0][k80] = *(const uint4*)(yh + brow0 + k0 + k80);
    *(uint4*)&Bs[0][r1][k81] = *(const uint4*)(yh + brow1 + k0 + k81);
    *(uint4*)&Bs[1][r0][k80] = *(const uint4*)(yl + brow0 + k0 + k80);
    *(uint4*)&Bs[1][r1][k81] = *(const uint4*)(yl + brow1 + k0 + k81);
    __syncthreads();
    int fr = lane & 15, kg = lane >> 4;
    bf16x8 ah[4], al[4], bh[4], bl[4];
    #pragma unroll
    for (int i = 0; i < 4; ++i) {
      ah[i] = *(const bf16x8*)&As[0][wrow + i * 16 + fr][kg * 8];
      al[i] = *(const bf16x8*)&As[1][wrow + i * 16 + fr][kg * 8];
      bh[i] = *(const bf16x8*)&Bs[0][wcol + i * 16 + fr][kg * 8];
      bl[i] = *(const bf16x8*)&Bs[1][wcol + i * 16 + fr][kg * 8];
    }
    #pragma unroll
    for (int i = 0; i < 4; ++i)
      #pragma unroll
      for (int j = 0; j < 4; ++j) {
        acc[i][j] = __builtin_amdgcn_mfma_f32_16x16x32_bf16(ah[i], bh[j], acc[i][j], 0, 0, 0);
        acc[i][j] = __builtin_amdgcn_mfma_f32_16x16x32_bf16(ah[i], bl[j], acc[i][j], 0, 0, 0);
        acc[i][j] = __builtin_amdgcn_mfma_f32_16x16x32_bf16(al[i], bh[j], acc[i][j], 0, 0, 0);
      }
    __syncthreads();
  }
  float tmax = -1.f;
  #pragma unroll
  for (int i = 0; i < 4; ++i) {
    #pragma unroll
    for (int j = 0; j < 4; ++j) {
      int col = bn * 128 + wcol + j * 16 + (lane & 15);
      #pragma unroll
      for (int r = 0; r < 4; ++r) {
        float d = acc[i][j][r];
        tmax = fmaxf(tmax, d);
        int q = __float2int_rn(fminf(fmaxf(d * 65536.f, -32767.f), 32767.f));
        int row = bm * 128 + wrow + i * 16 + (lane >> 4) * 4 + r;
        D16[(size_t)row * NDIM + col] = (short)q;
      }
    }
  }
  __shared__ float sm[4];
  #pragma unroll
  for (int off = 32; off; off >>= 1) tmax = fmaxf(tmax, __shfl_down(tmax, off));
  if (lane == 0) sm[wid] = tmax;
  __syncthreads();
  if (tid == 0) {
    float m = fmaxf(fmaxf(sm[0], sm[1]), fmaxf(sm[2], sm[3]));
    atomicMax((int*)maxdot, __float_as_int(fmaxf(m, 0.f)));
  }
}

// ---------- lightweight sharded grid barrier (agent scope) ----------
__device__ __forceinline__ void gridbar(unsigned* cnt, unsigned* root, int b, int blk) {
  __syncthreads();
  if (threadIdx.x == 0) {
    unsigned* sc = cnt + ((b << 4) + (blk & 15)) * 16;
    unsigned old = __hip_atomic_fetch_add(sc, 1u, __ATOMIC_ACQ_REL, __HIP_MEMORY_SCOPE_AGENT);
    if (old == 15u) {
      __hip_atomic_fetch_add(root + b * 16, 1u, __ATOMIC_ACQ_REL, __HIP_MEMORY_SCOPE_AGENT);
    }
    while (__hip_atomic_load(root + b * 16, __ATOMIC_RELAXED, __HIP_MEMORY_SCOPE_AGENT) < 16u)
      __builtin_amdgcn_s_sleep(1);
    (void)__hip_atomic_load(root + b * 16, __ATOMIC_ACQUIRE, __HIP_MEMORY_SCOPE_AGENT);
  }
  __syncthreads();
}

// ---------- split-ownership persistent solver: 1 grid barrier / iteration ----------
// blocks 0..127: own 32 rows each  (full row in regs)  -> row sums -> phi
// blocks 128..255: own 32 cols each (full col in regs) -> col sums -> psi (+loss at t=30)
__global__ __launch_bounds__(1024, 4)
void solve_kernel(const short* __restrict__ D16,
                  float* __restrict__ phi_g, float* __restrict__ psi_g,
                  const float* __restrict__ maxdot,
                  unsigned* psimaxS, unsigned* phimaxS,
                  const float* __restrict__ colM,
                  float* lossacc, float* __restrict__ out,
                  unsigned* cnt, unsigned* root) {
  __shared__ float vec_lds[4096];   // cross vector + shift
  __shared__ float red[32][33];
  __shared__ float own[32];         // raw phi (rowside) / psi (colside) of owned stripe
  int tid = threadIdx.x;
  int blk = blockIdx.x;
  bool rowside = blk < 128;
  int lloc = tid & 31;              // owned-dim local index
  int chunk = tid >> 5;             // 0..31, 128-wide chunk of the other dim
  int obase = (rowside ? blk : (blk - 128)) * 32;
  float md = maxdot[0];

  // one-time: 128 D16 entries per thread into 32 int2 (64 VGPR)
  int2 d[32];
  if (rowside) {
    const short* src = D16 + (size_t)(obase + lloc) * NDIM + chunk * 128;
    #pragma unroll
    for (int g = 0; g < 32; ++g) d[g] = *(const int2*)(src + 4 * g);
  } else {
    int j = obase + lloc;
    #pragma unroll
    for (int g = 0; g < 32; ++g) {
      int rr = chunk * 128 + 4 * g;
      unsigned s0 = (unsigned short)(unsigned)D16[(size_t)(rr + 0) * NDIM + j];
      unsigned s1 = (unsigned short)(unsigned)D16[(size_t)(rr + 1) * NDIM + j];
      unsigned s2 = (unsigned short)(unsigned)D16[(size_t)(rr + 2) * NDIM + j];
      unsigned s3 = (unsigned short)(unsigned)D16[(size_t)(rr + 3) * NDIM + j];
      d[g].x = (int)(s0 | (s1 << 16));
      d[g].y = (int)(s2 | (s3 << 16));
    }
  }
  if (tid < 32) own[tid] = -6.f;

  for (int t = 1; t <= N_ITER; ++t) {
    float sD  = (float)((double)t * (TWO_KAPPA / 65536.0));
    float tCL = (float)((double)t * CLCONST);
    float s2k = (float)((double)t * TWO_KAPPA);
    float tLmax = fmaf(s2k, md, tCL);
    float psimax, phimax;
    if (t == 1) { psimax = phimax = -6.f; }
    else {
      unsigned up = 0, uf = 0;
      #pragma unroll
      for (int s = 0; s < 16; ++s) {
        unsigned a = ldvu(&psimaxS[(t << 4) + s]); up = a > up ? a : up;
        unsigned b = ldvu(&phimaxS[(t << 4) + s]); uf = b > uf ? b : uf;
      }
      psimax = decf(up); phimax = decf(uf);
    }
    float Sr = tLmax + psimax - 100.f;
    float Sc = tLmax + phimax - 100.f;
    float Wr = tCL - Sr;
    float Wc = tCL - Sc;
    float Sh = rowside ? Sr : Sc;

    // stage cross vector (+ shift) to LDS: rowside needs psi+Wr, colside phi+Wc
    {
      float add = rowside ? Wr : Wc;
      float4 v;
      if (t == 1) {
        float c = -6.f + add;
        v = make_float4(c, c, c, c);
      } else {
        const float* src = rowside ? psi_g : phi_g;
        v = *(const float4*)(src + tid * 4);
        v.x += add; v.y += add; v.z += add; v.w += add;
      }
      *(float4*)&vec_lds[tid * 4] = v;
    }
    __syncthreads();

    // main accumulation: 128 entries, 1 exp2 + 1 fmaf + 1 add each
    float acc = 0.f;
    #pragma unroll
    for (int g = 0; g < 32; ++g) {
      float4 pv = *(const float4*)&vec_lds[chunk * 128 + 4 * g];  // broadcast read
      int2 dv = d[g];
      float d0 = (float)((short)(dv.x & 0xFFFF));
      float d1 = (float)(dv.x >> 16);
      float d2 = (float)((short)(dv.y & 0xFFFF));
      float d3 = (float)(dv.y >> 16);
      acc += exp2f(fmaf(d0, sD, pv.x));
      acc += exp2f(fmaf(d1, sD, pv.y));
      acc += exp2f(fmaf(d2, sD, pv.z));
      acc += exp2f(fmaf(d3, sD, pv.w));
    }
    red[lloc][chunk] = acc;
    __syncthreads();

    if (tid < 32) {
      float tot = 0.f;
      #pragma unroll
      for (int c = 0; c < 32; ++c) tot += red[tid][c];
      if (rowside || t < N_ITER) {
        float pn = 0.5f * (own[tid] - Sh - log2f(fmaxf(tot, 1e-30f)));
        own[tid] = pn;
        if (rowside) phi_g[obase + tid] = pn;
        else         psi_g[obase + tid] = pn;
        #pragma unroll
        for (int o = 16; o; o >>= 1) pn = fmaxf(pn, __shfl_down(pn, o));
        if (tid == 0) {
          unsigned* dst = rowside ? &phimaxS[((t + 1) << 4) + (blk & 15)]
                                  : &psimaxS[((t + 1) << 4) + (blk & 15)];
          atomicMax(dst, encf(pn));
        }
      } else {
        // colside, t == 30: colsum_j = 2^{psi30_j + Sc30} * tot
        float contrib = exp2f(log2f(fmaxf(tot, 1e-30f)) + own[tid] + Sc
                              + log2f(colM[obase + tid]));
        #pragma unroll
        for (int o = 16; o; o >>= 1) contrib += __shfl_down(contrib, o);
        if (tid == 0) atomicAdd(&lossacc[blk & 15], contrib);
      }
    }
    gridbar(cnt, root, t - 1, blk);
  }
  if (blk == 0 && tid == 0) {
    float tot = 0.f;
    #pragma unroll
    for (int s = 0; s < 16; ++s) tot += ldvf(&lossacc[s]);
    out[0] = tot * (1.f / ((float)MDIM * (float)MDIM));
  }
}

extern "C" void kernel_launch(void* const* d_in, const int* in_sizes, int n_in,
                              void* d_out, int out_size, void* d_ws, size_t ws_size,
                              hipStream_t stream) {
  const float* x = (const float*)d_in[0];
  const float* y = (const float*)d_in[1];
  float* out = (float*)d_out;

  char* ws = (char*)d_ws;
  size_t off = 0;
  auto alloc = [&](size_t bytes) -> void* {
    void* p = ws + off;
    off += (bytes + 255) & ~(size_t)255;
    return p;
  };
  short*    D16     = (short*)alloc((size_t)MDIM * NDIM * 2);      // 32 MB
  ushort*   xh      = (ushort*)alloc((size_t)MDIM * DDIM * 2);
  ushort*   xl      = (ushort*)alloc((size_t)MDIM * DDIM * 2);
  ushort*   yh      = (ushort*)alloc((size_t)NDIM * DDIM * 2);
  ushort*   yl      = (ushort*)alloc((size_t)NDIM * DDIM * 2);
  float*    xx      = (float*)alloc(MDIM * 4);
  float*    yy      = (float*)alloc(NDIM * 4);
  float*    sx      = (float*)alloc(DDIM * 4);
  float*    colM    = (float*)alloc(NDIM * 4);
  float*    Sxx     = (float*)alloc(4);
  float*    maxd    = (float*)alloc(4);
  unsigned* psimaxS = (unsigned*)alloc(64 * 16 * 4);
  unsigned* phimaxS = (unsigned*)alloc(64 * 16 * 4);
  float*    phi_g   = (float*)alloc(MDIM * 4);
  float*    psi_g   = (float*)alloc(NDIM * 4);
  float*    lossacc = (float*)alloc(16 * 4);
  unsigned* cnt     = (unsigned*)alloc(64 * 16 * 16 * 4);
  unsigned* root    = (unsigned*)alloc(64 * 16 * 4);

  hipMemsetAsync(Sxx, 0, 4, stream);
  hipMemsetAsync(maxd, 0, 4, stream);
  hipMemsetAsync(sx, 0, DDIM * 4, stream);
  hipMemsetAsync(psimaxS, 0, 64 * 16 * 4, stream);
  hipMemsetAsync(phimaxS, 0, 64 * 16 * 4, stream);
  hipMemsetAsync(lossacc, 0, 16 * 4, stream);
  hipMemsetAsync(cnt, 0, 64 * 16 * 16 * 4, stream);
  hipMemsetAsync(root, 0, 64 * 16 * 4, stream);

  norms_kernel<<<2048, 256, 0, stream>>>(x, y, xx, yy, Sxx);
  sx_kernel<<<256, 256, 0, stream>>>(x, sx);
  colM_kernel<<<1024, 256, 0, stream>>>(y, sx, yy, Sxx, colM);
  split_kernel<<<2048, 256, 0, stream>>>(x, y, xh, xl, yh, yl);
  gemm_mfma_kernel<<<1024, 256, 0, stream>>>(xh, xl, yh, yl, D16, maxd);

  void* kargs[] = {(void*)&D16, (void*)&phi_g, (void*)&psi_g,
                   (void*)&maxd, (void*)&psimaxS, (void*)&phimaxS,
                   (void*)&colM, (void*)&lossacc, (void*)&out,
                   (void*)&cnt, (void*)&root};
  hipLaunchCooperativeKernel((void*)solve_kernel, dim3(256), dim3(1024),
                             kargs, 0, stream);
}